// Round 9
// baseline (187.342 us; speedup 1.0000x reference)
//
#include <hip/hip_runtime.h>
#include <hip/hip_bf16.h>

typedef __attribute__((ext_vector_type(4))) float f32x4;
typedef __attribute__((ext_vector_type(8))) short s16x8;
typedef unsigned long long u64;

namespace {
constexpr int B_   = 8192;
constexpr int NT   = 256;          // 4 waves; wave h = head h
constexpr int SPB  = 8;            // samples per block (R5-proven)
constexpr int NBLK = B_ / SPB;     // 1024 blocks
// LDS layout
constexpr int XS_SH  = 48 * 136;                 // x staged bf16 [48][136] (rows 40..47 zero)
constexpr int RED_B  = XS_SH * 2;                // 13056: float redSQ[48][4][2]
constexpr int OUT_B  = RED_B + 48 * 4 * 2 * 4;   // 14592: float ost[40][132]
constexpr int OSTR   = 132;                      // 16B-aligned row stride
constexpr int POOL_B = OUT_B + 40 * OSTR * 4;    // 35712 B
}

__device__ __forceinline__ ushort f2b(float f) {
    union { __hip_bfloat16 h; ushort u; } cv;
    cv.h = __float2bfloat16(f);
    return cv.u;
}
// Software RNE pack (verified R2-R7). R8 post-mortem: v_cvt_pk_bf16_f32
// inline asm produced NaN — unverified ISA semantics; do NOT reintroduce
// without an interactive probe.
__device__ __forceinline__ u64 pack4(f32x4 v) {
    return (u64)f2b(v[0]) | ((u64)f2b(v[1]) << 16)
         | ((u64)f2b(v[2]) << 32) | ((u64)f2b(v[3]) << 48);
}
#define MFMA(a, b, c) __builtin_amdgcn_mfma_f32_16x16x32_bf16((a), (b), (c), 0, 0, 0)

// In-register C-layout -> A/B-fragment remap via __shfl pulls (verified
// R2-R7, absmax 0.0078). Source: lane (lr, lc_s) holds acc cols
// n = sel*16 + 4*lc_s + reg (sel 0/1 -> A,B u64 of 4 bf16). Target: lane
// (lr, lc) needs shorts n = 8lc..8lc+7 -> pull ints from lanes
// sl0 = lr+32*(lc&1), sl1 = sl0+16; b-side for lc>=2.
__device__ __forceinline__ s16x8 remap(u64 A, u64 B, int sl0, int sl1, bool hi) {
    const int a0 = (int)A, a1 = (int)(A >> 32);
    const int b0 = (int)B, b1 = (int)(B >> 32);
    const int pa0 = __shfl(a0, sl0), pa2 = __shfl(a0, sl1);
    const int pa1 = __shfl(a1, sl0), pa3 = __shfl(a1, sl1);
    const int pb0 = __shfl(b0, sl0), pb2 = __shfl(b0, sl1);
    const int pb1 = __shfl(b1, sl0), pb3 = __shfl(b1, sl1);
    union { int i[4]; s16x8 v; } r;
    r.i[0] = hi ? pb0 : pa0;
    r.i[1] = hi ? pb1 : pa1;
    r.i[2] = hi ? pb2 : pa2;
    r.i[3] = hi ? pb3 : pa3;
    return r.v;
}
// B-half identically zero (j-padding): hi lanes take 0, skip 4 shuffles.
__device__ __forceinline__ s16x8 remapA(u64 A, int sl0, int sl1, bool hi) {
    const int a0 = (int)A, a1 = (int)(A >> 32);
    const int pa0 = __shfl(a0, sl0), pa2 = __shfl(a0, sl1);
    const int pa1 = __shfl(a1, sl0), pa3 = __shfl(a1, sl1);
    union { int i[4]; s16x8 v; } r;
    r.i[0] = hi ? 0 : pa0;
    r.i[1] = hi ? 0 : pa1;
    r.i[2] = hi ? 0 : pa2;
    r.i[3] = hi ? 0 : pa3;
    return r.v;
}

// Wt[m][n][k] = W_m[k][n] bf16. m 0..3: Wq[m] (m=0 doubles as key matrix per
// merge='no' quirk); m=4: Wv; m=5: Wr.  192 KB total.
__global__ void convert_w(const float* __restrict__ Wq,
                          const float* __restrict__ Wv,
                          const float* __restrict__ Wr,
                          ushort* __restrict__ Wt)
{
    int idx = blockIdx.x * 256 + threadIdx.x;
    if (idx >= 6 * 16384) return;
    int m = idx >> 14, r = idx & 16383, n = r >> 7, k = r & 127;
    float v;
    if (m < 4)       v = Wq[(size_t)m * 16384 + k * 128 + n];
    else if (m == 4) v = Wv[k * 128 + n];
    else             v = Wr[k * 128 + n];
    Wt[idx] = f2b(v);
}

// (NT,2): cap 256 total regs/wave — the proven no-spill regime (R5: zero
// scratch, 152.9 us). Structure = R5 exactly. Adds only the two micro-opts
// proven in passing rounds R6/R7: kk=0 zero-peel + direct v_exp_f32.
__global__ __launch_bounds__(NT, 2)
void mdr_fused11(const float* __restrict__ inputs,
                 const int* __restrict__ dom,
                 const ushort* __restrict__ Wt,
                 const float* __restrict__ ln_g,
                 const float* __restrict__ ln_b,
                 float* __restrict__ out)
{
    __shared__ __align__(16) char pool[POOL_B];
    ushort* sp = reinterpret_cast<ushort*>(pool);
    float* red = reinterpret_cast<float*>(pool + RED_B);
    float* ost = reinterpret_cast<float*>(pool + OUT_B);

    const int t = threadIdx.x;
    const int w = t >> 6, l = t & 63;
    const int lr = l & 15, lc = l >> 4;
    const int sl0 = lr + 32 * (lc & 1);
    const int sl1 = sl0 + 16;
    const bool hi = lc >= 2;
    const int h = w;                       // wave = head
    const size_t s0 = (size_t)blockIdx.x * SPB;
    const float4* in4 = reinterpret_cast<const float4*>(inputs);
    float4* out4g = reinterpret_cast<float4*>(out);

    // zero XS pad rows 40..47 once (covered by first B1)
    {
        const int row = 40 + (t >> 5), c = (t & 31) * 4;
        *reinterpret_cast<u64*>(&sp[row * 136 + c]) = 0ull;
    }

    float4 xp[5];
    #pragma unroll
    for (int j = 0; j < 5; ++j)
        xp[j] = in4[s0 * 1280 + t + 256 * j];

    #pragma unroll 1
    for (int s = 0; s < SPB; ++s) {
        // ---- stage x -> XS (bf16) ----
        #pragma unroll
        for (int j = 0; j < 5; ++j) {
            const int idx4 = t + 256 * j;
            const int row = idx4 >> 5, c4 = idx4 & 31;
            u64 pk = (u64)f2b(xp[j].x) | ((u64)f2b(xp[j].y) << 16)
                   | ((u64)f2b(xp[j].z) << 32) | ((u64)f2b(xp[j].w) << 48);
            *reinterpret_cast<u64*>(&sp[row * 136 + c4 * 4]) = pk;
        }
        const int d = dom[s0 + s] - 1;
        __syncthreads();                                   // B1: XS ready
        // (B1 also fences ost/red reuse: read-pass(s-1) precedes stage(s)
        //  precedes B1(s) in every wave's program order.)

        const ushort* wq = Wt + (size_t)d * 16384 + (h * 32) * 128;
        const ushort* wk = Wt + (h * 32) * 128;            // key = Wq[0]
        const ushort* wv = Wt + (size_t)4 * 16384 + (h * 32) * 128;
        const ushort* wr = Wt + (size_t)5 * 16384 + (h * 32) * 128;
        const int wo = lr * 128 + lc * 8;
        const f32x4 zz = {0.f, 0.f, 0.f, 0.f};

        // ---- pass 1: q, k projections (kk=0 zero-peeled) ----
        f32x4 aq[2][3], ak[2][3];
        #pragma unroll
        for (int kk = 0; kk < 4; ++kk) {
            s16x8 xf[3];
            #pragma unroll
            for (int rt = 0; rt < 3; ++rt)
                xf[rt] = *reinterpret_cast<const s16x8*>(&sp[(rt * 16 + lr) * 136 + kk * 32 + lc * 8]);
            #pragma unroll
            for (int nt = 0; nt < 2; ++nt) {
                const int o = nt * 2048 + wo + kk * 32;
                const s16x8 qf = *reinterpret_cast<const s16x8*>(wq + o);
                const s16x8 kf = *reinterpret_cast<const s16x8*>(wk + o);
                #pragma unroll
                for (int rt = 0; rt < 3; ++rt) {
                    aq[nt][rt] = MFMA(qf, xf[rt], kk == 0 ? zz : aq[nt][rt]);  // q^T: [n][xrow]
                    ak[nt][rt] = MFMA(kf, xf[rt], kk == 0 ? zz : ak[nt][rt]);  // k^T
                }
            }
        }
        // in-register remap to QK fragments (q/k rows >= 40 are exact zeros)
        s16x8 qfr[3], kfr[3];
        #pragma unroll
        for (int tt = 0; tt < 3; ++tt) {
            qfr[tt] = remap(pack4(aq[0][tt]), pack4(aq[1][tt]), sl0, sl1, hi);
            kfr[tt] = remap(pack4(ak[0][tt]), pack4(ak[1][tt]), sl0, sl1, hi);
        }

        // ---- pass 2: v, r projections (kk=0 zero-peeled) ----
        f32x4 av[3][2], ar[2][3];
        #pragma unroll
        for (int kk = 0; kk < 4; ++kk) {
            s16x8 xf[3];
            #pragma unroll
            for (int rt = 0; rt < 3; ++rt)
                xf[rt] = *reinterpret_cast<const s16x8*>(&sp[(rt * 16 + lr) * 136 + kk * 32 + lc * 8]);
            #pragma unroll
            for (int nt = 0; nt < 2; ++nt) {
                const int o = nt * 2048 + wo + kk * 32;
                const s16x8 vf = *reinterpret_cast<const s16x8*>(wv + o);
                const s16x8 rf = *reinterpret_cast<const s16x8*>(wr + o);
                #pragma unroll
                for (int rt = 0; rt < 3; ++rt) {
                    av[rt][nt] = MFMA(xf[rt], vf, kk == 0 ? zz : av[rt][nt]);  // v: [xrow][e]
                    ar[nt][rt] = MFMA(rf, xf[rt], kk == 0 ? zz : ar[nt][rt]);  // r^T
                }
            }
        }
        u64 pkV[3][2];
        #pragma unroll
        for (int rt = 0; rt < 3; ++rt)
            #pragma unroll
            for (int nt = 0; nt < 2; ++nt)
                pkV[rt][nt] = pack4(av[rt][nt]);

        // ---- QK^T fused with softmax per it-row block ----
        // S^T[j][i] = mfma(A=k, B=q); lane holds S[i=it*16+lr][j=jt*16+4lc+reg]
        // p = e^(S/sqrt(32)) = 2^(S * log2e/sqrt(32)); v_exp_f32 is 2^x.
        const float l2scale = 0.2550348615f;   // log2(e)/sqrt(32)
        u64 pkP[3][3];
        float inv[3];
        #pragma unroll
        for (int it = 0; it < 3; ++it) {
            f32x4 sr[3];
            #pragma unroll
            for (int jt = 0; jt < 3; ++jt)
                sr[jt] = MFMA(kfr[jt], qfr[it], zz);
            float sum = 0.f;
            #pragma unroll
            for (int jt = 0; jt < 3; ++jt) {
                f32x4 pv;
                #pragma unroll
                for (int reg = 0; reg < 4; ++reg) {
                    float p;
                    if (jt == 2 && lc >= 2) {
                        p = 0.f;                            // mask j>=40
                    } else {
                        const float e2 = sr[jt][reg] * l2scale;
                        asm("v_exp_f32 %0, %1" : "=v"(p) : "v"(e2));
                    }
                    pv[reg] = p;
                    sum += p;
                }
                pkP[it][jt] = pack4(pv);
            }
            sum += __shfl_xor(sum, 16);
            sum += __shfl_xor(sum, 32);
            inv[it] = 1.f / sum;           // folded into epilogue (P unnormalized)
        }

        // prefetch next sample (covered by PV..B2..read-pass)
        if (s + 1 < SPB) {
            #pragma unroll
            for (int j = 0; j < 5; ++j)
                xp[j] = in4[(s0 + s + 1) * 1280 + t + 256 * j];
        }

        // ---- PV, transposed: O^T[e][i] = mfma(A=v^T, B=P) ----
        f32x4 o[2][3];
        #pragma unroll
        for (int et = 0; et < 2; ++et)
            #pragma unroll
            for (int it = 0; it < 3; ++it)
                o[et][it] = f32x4{0.f, 0.f, 0.f, 0.f};
        #pragma unroll
        for (int kk = 0; kk < 2; ++kk) {
            s16x8 vfr[2], pfr[3];
            #pragma unroll
            for (int et = 0; et < 2; ++et)
                vfr[et] = kk ? remapA(pkV[2][et], sl0, sl1, hi)
                             : remap(pkV[0][et], pkV[1][et], sl0, sl1, hi);
            #pragma unroll
            for (int it = 0; it < 3; ++it)
                pfr[it] = kk ? remapA(pkP[it][2], sl0, sl1, hi)
                             : remap(pkP[it][0], pkP[it][1], sl0, sl1, hi);
            #pragma unroll
            for (int et = 0; et < 2; ++et)
                #pragma unroll
                for (int it = 0; it < 3; ++it)
                    o[et][it] = MFMA(vfr[et], pfr[it], o[et][it]);
        }

        // ---- epilogue: y = relu(o*inv + ar); LN partials; y -> ost ----
        #pragma unroll
        for (int it = 0; it < 3; ++it) {
            const bool valid = !(it == 2 && lr >= 8);      // rows < 40
            float sa = 0.f, qa2 = 0.f;
            float4 yv[2];
            #pragma unroll
            for (int et = 0; et < 2; ++et)
                #pragma unroll
                for (int reg = 0; reg < 4; ++reg) {
                    float yy = fmaxf(fmaf(o[et][it][reg], inv[it], ar[et][it][reg]), 0.f);
                    (&yv[et].x)[reg] = yy;
                    sa += yy;
                    qa2 = fmaf(yy, yy, qa2);
                }
            sa  += __shfl_xor(sa, 16);   sa  += __shfl_xor(sa, 32);
            qa2 += __shfl_xor(qa2, 16);  qa2 += __shfl_xor(qa2, 32);
            if (lc == 0)
                *reinterpret_cast<float2*>(&red[((it * 16 + lr) * 4 + w) * 2]) =
                    make_float2(sa, qa2);
            if (valid) {
                #pragma unroll
                for (int et = 0; et < 2; ++et)
                    *reinterpret_cast<float4*>(&ost[(it * 16 + lr) * OSTR + h * 32 + et * 16 + 4 * lc]) = yv[et];
            }
        }
        __syncthreads();                                   // B2: red + ost ready

        // ---- read-pass: stats from red (broadcast), LN affine, coalesced store ----
        const int c4r = t & 31;
        const float4 gvr = *reinterpret_cast<const float4*>(&ln_g[d * 128 + c4r * 4]);
        const float4 bvr = *reinterpret_cast<const float4*>(&ln_b[d * 128 + c4r * 4]);
        const size_t b4 = (s0 + s) * 1280;
        #pragma unroll
        for (int j5 = 0; j5 < 5; ++j5) {
            const int idx = j5 * 256 + t;
            const int row = idx >> 5;                      // (idx & 31) == c4r
            const float4 r01 = *reinterpret_cast<const float4*>(&red[row * 8]);
            const float4 r23 = *reinterpret_cast<const float4*>(&red[row * 8 + 4]);
            const float sa = r01.x + r01.z + r23.x + r23.z;
            const float q2 = r01.y + r01.w + r23.y + r23.w;
            const float mean = sa * (1.f / 128.f);
            const float rstd = rsqrtf(q2 * (1.f / 128.f) - mean * mean + 1e-6f);
            const float4 v = *reinterpret_cast<const float4*>(&ost[row * OSTR + c4r * 4]);
            float4 ov;
            ov.x = (v.x - mean) * rstd * gvr.x + bvr.x;
            ov.y = (v.y - mean) * rstd * gvr.y + bvr.y;
            ov.z = (v.z - mean) * rstd * gvr.z + bvr.z;
            ov.w = (v.w - mean) * rstd * gvr.w + bvr.w;
            out4g[b4 + idx] = ov;
        }
    }
}

extern "C" void kernel_launch(void* const* d_in, const int* in_sizes, int n_in,
                              void* d_out, int out_size, void* d_ws, size_t ws_size,
                              hipStream_t stream)
{
    const float* inputs = (const float*)d_in[0];
    const int*   dm     = (const int*)d_in[1];
    const float* Wq     = (const float*)d_in[2];
    const float* Wv     = (const float*)d_in[3];
    const float* Wr     = (const float*)d_in[4];
    const float* g      = (const float*)d_in[5];
    const float* bt     = (const float*)d_in[6];
    float* outp         = (float*)d_out;
    ushort* Wt          = (ushort*)d_ws;   // 6*128*128*2 = 192 KB

    convert_w<<<(6 * 16384 + 255) / 256, 256, 0, stream>>>(Wq, Wv, Wr, Wt);
    mdr_fused11<<<NBLK, NT, 0, stream>>>(inputs, dm, Wt, g, bt, outp);
}

// Round 10
// 151.011 us; speedup vs baseline: 1.2406x; 1.2406x over previous
//
#include <hip/hip_runtime.h>
#include <hip/hip_bf16.h>

typedef __attribute__((ext_vector_type(4))) float f32x4;
typedef __attribute__((ext_vector_type(8))) short s16x8;
typedef unsigned long long u64;

namespace {
constexpr int B_   = 8192;
constexpr int NT   = 256;          // 4 waves; wave h = head h
constexpr int SPB  = 8;            // samples per block (R5-proven)
constexpr int NBLK = B_ / SPB;     // 1024 blocks
// LDS layout
constexpr int XS_SH  = 48 * 136;                 // x staged bf16 [48][136] (rows 40..47 zero)
constexpr int RED_B  = XS_SH * 2;                // 13056: float redSQ[48][4][2]
constexpr int OUT_B  = RED_B + 48 * 4 * 2 * 4;   // 14592: float ost[40][132]
constexpr int OSTR   = 132;                      // 16B-aligned row stride
constexpr int POOL_B = OUT_B + 40 * OSTR * 4;    // 35712 B
}

__device__ __forceinline__ ushort f2b(float f) {
    union { __hip_bfloat16 h; ushort u; } cv;
    cv.h = __float2bfloat16(f);
    return cv.u;
}
// Software RNE pack (verified R2-R9). R8: v_cvt_pk_bf16_f32 asm = NaN; banned.
__device__ __forceinline__ u64 pack4(f32x4 v) {
    return (u64)f2b(v[0]) | ((u64)f2b(v[1]) << 16)
         | ((u64)f2b(v[2]) << 32) | ((u64)f2b(v[3]) << 48);
}
// Zero-cost fragment build: concat two packed u64s. Valid because BOTH MFMA
// operands are fed through the SAME slot->contraction-index bijection
// pi(lc,s) = {4lc+s (s<4), 16+4lc+s-4 (s>=4)} — MFMA's sum over k is
// permutation-invariant when A and B share pi. Replaces the R2-R9 shuffle
// remap (8 ds_bpermute + 4 cndmask each) with zero instructions.
__device__ __forceinline__ s16x8 cat(u64 A, u64 B) {
    union { u64 q[2]; s16x8 v; } r;
    r.q[0] = A; r.q[1] = B;
    return r.v;
}
#define MFMA(a, b, c) __builtin_amdgcn_mfma_f32_16x16x32_bf16((a), (b), (c), 0, 0, 0)

// Wt[m][n][k] = W_m[k][n] bf16. m 0..3: Wq[m] (m=0 doubles as key matrix per
// merge='no' quirk); m=4: Wv; m=5: Wr.  192 KB total.
__global__ void convert_w(const float* __restrict__ Wq,
                          const float* __restrict__ Wv,
                          const float* __restrict__ Wr,
                          ushort* __restrict__ Wt)
{
    int idx = blockIdx.x * 256 + threadIdx.x;
    if (idx >= 6 * 16384) return;
    int m = idx >> 14, r = idx & 16383, n = r >> 7, k = r & 127;
    float v;
    if (m < 4)       v = Wq[(size_t)m * 16384 + k * 128 + n];
    else if (m == 4) v = Wv[k * 128 + n];
    else             v = Wr[k * 128 + n];
    Wt[idx] = f2b(v);
}

// (NT,2): cap 256 total regs/wave — the proven no-spill regime. Source = R5
// EXACTLY (152.9 us; R9 proved even "neutral" micro-opts perturb allocation
// into spills) except the shuffle remap is deleted via pi-consistent concat.
__global__ __launch_bounds__(NT, 2)
void mdr_fused12(const float* __restrict__ inputs,
                 const int* __restrict__ dom,
                 const ushort* __restrict__ Wt,
                 const float* __restrict__ ln_g,
                 const float* __restrict__ ln_b,
                 float* __restrict__ out)
{
    __shared__ __align__(16) char pool[POOL_B];
    ushort* sp = reinterpret_cast<ushort*>(pool);
    float* red = reinterpret_cast<float*>(pool + RED_B);
    float* ost = reinterpret_cast<float*>(pool + OUT_B);

    const int t = threadIdx.x;
    const int w = t >> 6, l = t & 63;
    const int lr = l & 15, lc = l >> 4;
    const int h = w;                       // wave = head
    const size_t s0 = (size_t)blockIdx.x * SPB;
    const float4* in4 = reinterpret_cast<const float4*>(inputs);
    float4* out4g = reinterpret_cast<float4*>(out);

    // zero XS pad rows 40..47 once (covered by first B1)
    {
        const int row = 40 + (t >> 5), c = (t & 31) * 4;
        *reinterpret_cast<u64*>(&sp[row * 136 + c]) = 0ull;
    }

    float4 xp[5];
    #pragma unroll
    for (int j = 0; j < 5; ++j)
        xp[j] = in4[s0 * 1280 + t + 256 * j];

    #pragma unroll 1
    for (int s = 0; s < SPB; ++s) {
        // ---- stage x -> XS (bf16) ----
        #pragma unroll
        for (int j = 0; j < 5; ++j) {
            const int idx4 = t + 256 * j;
            const int row = idx4 >> 5, c4 = idx4 & 31;
            u64 pk = (u64)f2b(xp[j].x) | ((u64)f2b(xp[j].y) << 16)
                   | ((u64)f2b(xp[j].z) << 32) | ((u64)f2b(xp[j].w) << 48);
            *reinterpret_cast<u64*>(&sp[row * 136 + c4 * 4]) = pk;
        }
        const int d = dom[s0 + s] - 1;
        __syncthreads();                                   // B1: XS ready
        // (B1 also fences ost/red reuse: read-pass(s-1) precedes stage(s)
        //  precedes B1(s) in every wave's program order.)

        const ushort* wq = Wt + (size_t)d * 16384 + (h * 32) * 128;
        const ushort* wk = Wt + (h * 32) * 128;            // key = Wq[0]
        const ushort* wv = Wt + (size_t)4 * 16384 + (h * 32) * 128;
        const ushort* wr = Wt + (size_t)5 * 16384 + (h * 32) * 128;
        const int wo = lr * 128 + lc * 8;

        // ---- pass 1: q, k projections ----
        f32x4 aq[2][3], ak[2][3];
        #pragma unroll
        for (int nt = 0; nt < 2; ++nt)
            #pragma unroll
            for (int rt = 0; rt < 3; ++rt) {
                aq[nt][rt] = f32x4{0.f, 0.f, 0.f, 0.f};
                ak[nt][rt] = f32x4{0.f, 0.f, 0.f, 0.f};
            }
        #pragma unroll
        for (int kk = 0; kk < 4; ++kk) {
            s16x8 xf[3];
            #pragma unroll
            for (int rt = 0; rt < 3; ++rt)
                xf[rt] = *reinterpret_cast<const s16x8*>(&sp[(rt * 16 + lr) * 136 + kk * 32 + lc * 8]);
            #pragma unroll
            for (int nt = 0; nt < 2; ++nt) {
                const int o = nt * 2048 + wo + kk * 32;
                const s16x8 qf = *reinterpret_cast<const s16x8*>(wq + o);
                const s16x8 kf = *reinterpret_cast<const s16x8*>(wk + o);
                #pragma unroll
                for (int rt = 0; rt < 3; ++rt) {
                    aq[nt][rt] = MFMA(qf, xf[rt], aq[nt][rt]);  // q^T: [n][xrow]
                    ak[nt][rt] = MFMA(kf, xf[rt], ak[nt][rt]);  // k^T
                }
            }
        }
        // pi-consistent fragments: slots = {4lc+s, 16+4lc+s-4}, lane lr = row
        // (q/k rows >= 40 are exact zeros via XS padding)
        s16x8 qfr[3], kfr[3];
        #pragma unroll
        for (int tt = 0; tt < 3; ++tt) {
            qfr[tt] = cat(pack4(aq[0][tt]), pack4(aq[1][tt]));
            kfr[tt] = cat(pack4(ak[0][tt]), pack4(ak[1][tt]));
        }

        // ---- pass 2: v, r projections (ar stays in registers) ----
        f32x4 av[3][2], ar[2][3];
        #pragma unroll
        for (int nt = 0; nt < 2; ++nt)
            #pragma unroll
            for (int rt = 0; rt < 3; ++rt) {
                av[rt][nt] = f32x4{0.f, 0.f, 0.f, 0.f};
                ar[nt][rt] = f32x4{0.f, 0.f, 0.f, 0.f};
            }
        #pragma unroll
        for (int kk = 0; kk < 4; ++kk) {
            s16x8 xf[3];
            #pragma unroll
            for (int rt = 0; rt < 3; ++rt)
                xf[rt] = *reinterpret_cast<const s16x8*>(&sp[(rt * 16 + lr) * 136 + kk * 32 + lc * 8]);
            #pragma unroll
            for (int nt = 0; nt < 2; ++nt) {
                const int o = nt * 2048 + wo + kk * 32;
                const s16x8 vf = *reinterpret_cast<const s16x8*>(wv + o);
                const s16x8 rf = *reinterpret_cast<const s16x8*>(wr + o);
                #pragma unroll
                for (int rt = 0; rt < 3; ++rt) {
                    av[rt][nt] = MFMA(xf[rt], vf, av[rt][nt]);  // v: [xrow][e]
                    ar[nt][rt] = MFMA(rf, xf[rt], ar[nt][rt]);  // r^T
                }
            }
        }
        u64 pkV[3][2];
        #pragma unroll
        for (int rt = 0; rt < 3; ++rt)
            #pragma unroll
            for (int nt = 0; nt < 2; ++nt)
                pkV[rt][nt] = pack4(av[rt][nt]);

        // ---- QK^T fused with softmax per it-row block ----
        // S^T[j][i] = mfma(A=k, B=q); pi cancels (both operands share it).
        // Output C-layout is HW-fixed: lane holds S[i=it*16+lr][j=jt*16+4lc+reg]
        const float scale = 0.17677669529663689f;   // 1/sqrt(32)
        u64 pkP[3][3];
        float inv[3];
        #pragma unroll
        for (int it = 0; it < 3; ++it) {
            f32x4 sr[3];
            #pragma unroll
            for (int jt = 0; jt < 3; ++jt) {
                f32x4 z = {0.f, 0.f, 0.f, 0.f};
                sr[jt] = MFMA(kfr[jt], qfr[it], z);
            }
            float sum = 0.f;
            #pragma unroll
            for (int jt = 0; jt < 3; ++jt) {
                f32x4 pv;
                #pragma unroll
                for (int reg = 0; reg < 4; ++reg) {
                    float p = (jt == 2 && lc >= 2) ? 0.f : __expf(sr[jt][reg] * scale);  // mask j>=40
                    pv[reg] = p;
                    sum += p;
                }
                pkP[it][jt] = pack4(pv);
            }
            sum += __shfl_xor(sum, 16);
            sum += __shfl_xor(sum, 32);
            inv[it] = 1.f / sum;           // folded into epilogue (P unnormalized)
        }

        // prefetch next sample (covered by PV..B2..read-pass)
        if (s + 1 < SPB) {
            #pragma unroll
            for (int j = 0; j < 5; ++j)
                xp[j] = in4[(s0 + s + 1) * 1280 + t + 256 * j];
        }

        // ---- PV, transposed: O^T[e][i] = mfma(A=v^T, B=P) ----
        // kk=0: slots j = {4lc+s, 16+4lc+s-4}; kk=1: {32+4lc+s, 0-pad} —
        // A and B zero together on the pad slots, so pairing stays exact.
        f32x4 o[2][3];
        #pragma unroll
        for (int et = 0; et < 2; ++et)
            #pragma unroll
            for (int it = 0; it < 3; ++it)
                o[et][it] = f32x4{0.f, 0.f, 0.f, 0.f};
        #pragma unroll
        for (int kk = 0; kk < 2; ++kk) {
            s16x8 vfr[2], pfr[3];
            #pragma unroll
            for (int et = 0; et < 2; ++et)
                vfr[et] = kk ? cat(pkV[2][et], 0ull)
                             : cat(pkV[0][et], pkV[1][et]);
            #pragma unroll
            for (int it = 0; it < 3; ++it)
                pfr[it] = kk ? cat(pkP[it][2], 0ull)
                             : cat(pkP[it][0], pkP[it][1]);
            #pragma unroll
            for (int et = 0; et < 2; ++et)
                #pragma unroll
                for (int it = 0; it < 3; ++it)
                    o[et][it] = MFMA(vfr[et], pfr[it], o[et][it]);
        }

        // ---- epilogue: y = relu(o*inv + ar); LN partials; y -> ost ----
        #pragma unroll
        for (int it = 0; it < 3; ++it) {
            const bool valid = !(it == 2 && lr >= 8);      // rows < 40
            float sa = 0.f, qa2 = 0.f;
            float4 yv[2];
            #pragma unroll
            for (int et = 0; et < 2; ++et)
                #pragma unroll
                for (int reg = 0; reg < 4; ++reg) {
                    float yy = fmaxf(fmaf(o[et][it][reg], inv[it], ar[et][it][reg]), 0.f);
                    (&yv[et].x)[reg] = yy;
                    sa += yy;
                    qa2 = fmaf(yy, yy, qa2);
                }
            sa  += __shfl_xor(sa, 16);   sa  += __shfl_xor(sa, 32);
            qa2 += __shfl_xor(qa2, 16);  qa2 += __shfl_xor(qa2, 32);
            if (lc == 0)
                *reinterpret_cast<float2*>(&red[((it * 16 + lr) * 4 + w) * 2]) =
                    make_float2(sa, qa2);
            if (valid) {
                #pragma unroll
                for (int et = 0; et < 2; ++et)
                    *reinterpret_cast<float4*>(&ost[(it * 16 + lr) * OSTR + h * 32 + et * 16 + 4 * lc]) = yv[et];
            }
        }
        __syncthreads();                                   // B2: red + ost ready

        // ---- read-pass: stats from red (broadcast), LN affine, coalesced store ----
        const int c4r = t & 31;
        const float4 gvr = *reinterpret_cast<const float4*>(&ln_g[d * 128 + c4r * 4]);
        const float4 bvr = *reinterpret_cast<const float4*>(&ln_b[d * 128 + c4r * 4]);
        const size_t b4 = (s0 + s) * 1280;
        #pragma unroll
        for (int j5 = 0; j5 < 5; ++j5) {
            const int idx = j5 * 256 + t;
            const int row = idx >> 5;                      // (idx & 31) == c4r
            const float4 r01 = *reinterpret_cast<const float4*>(&red[row * 8]);
            const float4 r23 = *reinterpret_cast<const float4*>(&red[row * 8 + 4]);
            const float sa = r01.x + r01.z + r23.x + r23.z;
            const float q2 = r01.y + r01.w + r23.y + r23.w;
            const float mean = sa * (1.f / 128.f);
            const float rstd = rsqrtf(q2 * (1.f / 128.f) - mean * mean + 1e-6f);
            const float4 v = *reinterpret_cast<const float4*>(&ost[row * OSTR + c4r * 4]);
            float4 ov;
            ov.x = (v.x - mean) * rstd * gvr.x + bvr.x;
            ov.y = (v.y - mean) * rstd * gvr.y + bvr.y;
            ov.z = (v.z - mean) * rstd * gvr.z + bvr.z;
            ov.w = (v.w - mean) * rstd * gvr.w + bvr.w;
            out4g[b4 + idx] = ov;
        }
    }
}

extern "C" void kernel_launch(void* const* d_in, const int* in_sizes, int n_in,
                              void* d_out, int out_size, void* d_ws, size_t ws_size,
                              hipStream_t stream)
{
    const float* inputs = (const float*)d_in[0];
    const int*   dm     = (const int*)d_in[1];
    const float* Wq     = (const float*)d_in[2];
    const float* Wv     = (const float*)d_in[3];
    const float* Wr     = (const float*)d_in[4];
    const float* g      = (const float*)d_in[5];
    const float* bt     = (const float*)d_in[6];
    float* outp         = (float*)d_out;
    ushort* Wt          = (ushort*)d_ws;   // 6*128*128*2 = 192 KB

    convert_w<<<(6 * 16384 + 255) / 256, 256, 0, stream>>>(Wq, Wv, Wr, Wt);
    mdr_fused12<<<NBLK, NT, 0, stream>>>(inputs, dm, Wt, g, bt, outp);
}

// Round 11
// 133.228 us; speedup vs baseline: 1.4062x; 1.1335x over previous
//
#include <hip/hip_runtime.h>
#include <hip/hip_bf16.h>

typedef __attribute__((ext_vector_type(4))) float f32x4;
typedef __attribute__((ext_vector_type(8))) short s16x8;
typedef unsigned long long u64;

namespace {
constexpr int B_   = 8192;
constexpr int NT   = 256;          // 4 waves; wave h = head h
constexpr int SPB  = 8;            // samples per block (R5-proven)
constexpr int NBLK = B_ / SPB;     // 1024 blocks
// LDS layout
constexpr int XS_SH  = 48 * 136;                 // x staged bf16 [48][136] (rows 40..47 zero)
constexpr int RED_B  = XS_SH * 2;                // 13056: float redSQ[48][4][2]
constexpr int OUT_B  = RED_B + 48 * 4 * 2 * 4;   // 14592: float ost[40][132]
constexpr int OSTR   = 132;                      // 16B-aligned row stride
constexpr int POOL_B = OUT_B + 40 * OSTR * 4;    // 35712 B
}

__device__ __forceinline__ ushort f2b(float f) {
    union { __hip_bfloat16 h; ushort u; } cv;
    cv.h = __float2bfloat16(f);
    return cv.u;
}
// Cheap f32->bf16 pair: round-half-up on raw bits ((u+0x8000)>>16). Valid
// because no NaN/inf can occur in this kernel's data; differs from RNE only
// on exact-tie mantissas (1 ulp, measure-zero). 5 VALU/pair vs ~14 for
// software RNE — pack4 was ~half the per-sample VALU load (R11 theory).
// Pure C bit ops (R8 rule: no unverified inline-asm primitives).
__device__ __forceinline__ unsigned bfpair(float x, float y) {
    const unsigned ux = __float_as_uint(x) + 0x8000u;
    const unsigned uy = __float_as_uint(y) + 0x8000u;
    return (ux >> 16) | (uy & 0xFFFF0000u);
}
__device__ __forceinline__ u64 pack4(f32x4 v) {
    return (u64)bfpair(v[0], v[1]) | ((u64)bfpair(v[2], v[3]) << 32);
}
__device__ __forceinline__ u64 pack4f(float4 v) {
    return (u64)bfpair(v.x, v.y) | ((u64)bfpair(v.z, v.w) << 32);
}
// Zero-cost fragment build: concat two packed u64s. Valid because BOTH MFMA
// operands are fed through the SAME slot->contraction-index bijection
// pi(lc,s) = {4lc+s (s<4), 16+4lc+s-4 (s>=4)} — MFMA's sum over k is
// permutation-invariant when A and B share pi (verified R10, absmax 0.0078).
__device__ __forceinline__ s16x8 cat(u64 A, u64 B) {
    union { u64 q[2]; s16x8 v; } r;
    r.q[0] = A; r.q[1] = B;
    return r.v;
}
#define MFMA(a, b, c) __builtin_amdgcn_mfma_f32_16x16x32_bf16((a), (b), (c), 0, 0, 0)

// Wt[m][n][k] = W_m[k][n] bf16 (full RNE — one-time cost, keeps weight
// accuracy max). m 0..3: Wq[m] (m=0 doubles as key matrix per merge='no'
// quirk); m=4: Wv; m=5: Wr.  192 KB total.
__global__ void convert_w(const float* __restrict__ Wq,
                          const float* __restrict__ Wv,
                          const float* __restrict__ Wr,
                          ushort* __restrict__ Wt)
{
    int idx = blockIdx.x * 256 + threadIdx.x;
    if (idx >= 6 * 16384) return;
    int m = idx >> 14, r = idx & 16383, n = r >> 7, k = r & 127;
    float v;
    if (m < 4)       v = Wq[(size_t)m * 16384 + k * 128 + n];
    else if (m == 4) v = Wv[k * 128 + n];
    else             v = Wr[k * 128 + n];
    Wt[idx] = f2b(v);
}

// (NT,2): cap 256 total regs/wave — the proven no-spill regime. Source = R10
// EXACTLY except pack4/pack4f/stage use the cheap round-half-up pack.
__global__ __launch_bounds__(NT, 2)
void mdr_fused13(const float* __restrict__ inputs,
                 const int* __restrict__ dom,
                 const ushort* __restrict__ Wt,
                 const float* __restrict__ ln_g,
                 const float* __restrict__ ln_b,
                 float* __restrict__ out)
{
    __shared__ __align__(16) char pool[POOL_B];
    ushort* sp = reinterpret_cast<ushort*>(pool);
    float* red = reinterpret_cast<float*>(pool + RED_B);
    float* ost = reinterpret_cast<float*>(pool + OUT_B);

    const int t = threadIdx.x;
    const int w = t >> 6, l = t & 63;
    const int lr = l & 15, lc = l >> 4;
    const int h = w;                       // wave = head
    const size_t s0 = (size_t)blockIdx.x * SPB;
    const float4* in4 = reinterpret_cast<const float4*>(inputs);
    float4* out4g = reinterpret_cast<float4*>(out);

    // zero XS pad rows 40..47 once (covered by first B1)
    {
        const int row = 40 + (t >> 5), c = (t & 31) * 4;
        *reinterpret_cast<u64*>(&sp[row * 136 + c]) = 0ull;
    }

    float4 xp[5];
    #pragma unroll
    for (int j = 0; j < 5; ++j)
        xp[j] = in4[s0 * 1280 + t + 256 * j];

    #pragma unroll 1
    for (int s = 0; s < SPB; ++s) {
        // ---- stage x -> XS (bf16, cheap pack) ----
        #pragma unroll
        for (int j = 0; j < 5; ++j) {
            const int idx4 = t + 256 * j;
            const int row = idx4 >> 5, c4 = idx4 & 31;
            *reinterpret_cast<u64*>(&sp[row * 136 + c4 * 4]) = pack4f(xp[j]);
        }
        const int d = dom[s0 + s] - 1;
        __syncthreads();                                   // B1: XS ready
        // (B1 also fences ost/red reuse: read-pass(s-1) precedes stage(s)
        //  precedes B1(s) in every wave's program order.)

        const ushort* wq = Wt + (size_t)d * 16384 + (h * 32) * 128;
        const ushort* wk = Wt + (h * 32) * 128;            // key = Wq[0]
        const ushort* wv = Wt + (size_t)4 * 16384 + (h * 32) * 128;
        const ushort* wr = Wt + (size_t)5 * 16384 + (h * 32) * 128;
        const int wo = lr * 128 + lc * 8;

        // ---- pass 1: q, k projections ----
        f32x4 aq[2][3], ak[2][3];
        #pragma unroll
        for (int nt = 0; nt < 2; ++nt)
            #pragma unroll
            for (int rt = 0; rt < 3; ++rt) {
                aq[nt][rt] = f32x4{0.f, 0.f, 0.f, 0.f};
                ak[nt][rt] = f32x4{0.f, 0.f, 0.f, 0.f};
            }
        #pragma unroll
        for (int kk = 0; kk < 4; ++kk) {
            s16x8 xf[3];
            #pragma unroll
            for (int rt = 0; rt < 3; ++rt)
                xf[rt] = *reinterpret_cast<const s16x8*>(&sp[(rt * 16 + lr) * 136 + kk * 32 + lc * 8]);
            #pragma unroll
            for (int nt = 0; nt < 2; ++nt) {
                const int o = nt * 2048 + wo + kk * 32;
                const s16x8 qf = *reinterpret_cast<const s16x8*>(wq + o);
                const s16x8 kf = *reinterpret_cast<const s16x8*>(wk + o);
                #pragma unroll
                for (int rt = 0; rt < 3; ++rt) {
                    aq[nt][rt] = MFMA(qf, xf[rt], aq[nt][rt]);  // q^T: [n][xrow]
                    ak[nt][rt] = MFMA(kf, xf[rt], ak[nt][rt]);  // k^T
                }
            }
        }
        // pi-consistent fragments: slots = {4lc+s, 16+4lc+s-4}, lane lr = row
        // (q/k rows >= 40 are exact zeros via XS padding)
        s16x8 qfr[3], kfr[3];
        #pragma unroll
        for (int tt = 0; tt < 3; ++tt) {
            qfr[tt] = cat(pack4(aq[0][tt]), pack4(aq[1][tt]));
            kfr[tt] = cat(pack4(ak[0][tt]), pack4(ak[1][tt]));
        }

        // ---- pass 2: v, r projections (ar stays in registers) ----
        f32x4 av[3][2], ar[2][3];
        #pragma unroll
        for (int nt = 0; nt < 2; ++nt)
            #pragma unroll
            for (int rt = 0; rt < 3; ++rt) {
                av[rt][nt] = f32x4{0.f, 0.f, 0.f, 0.f};
                ar[nt][rt] = f32x4{0.f, 0.f, 0.f, 0.f};
            }
        #pragma unroll
        for (int kk = 0; kk < 4; ++kk) {
            s16x8 xf[3];
            #pragma unroll
            for (int rt = 0; rt < 3; ++rt)
                xf[rt] = *reinterpret_cast<const s16x8*>(&sp[(rt * 16 + lr) * 136 + kk * 32 + lc * 8]);
            #pragma unroll
            for (int nt = 0; nt < 2; ++nt) {
                const int o = nt * 2048 + wo + kk * 32;
                const s16x8 vf = *reinterpret_cast<const s16x8*>(wv + o);
                const s16x8 rf = *reinterpret_cast<const s16x8*>(wr + o);
                #pragma unroll
                for (int rt = 0; rt < 3; ++rt) {
                    av[rt][nt] = MFMA(xf[rt], vf, av[rt][nt]);  // v: [xrow][e]
                    ar[nt][rt] = MFMA(rf, xf[rt], ar[nt][rt]);  // r^T
                }
            }
        }
        u64 pkV[3][2];
        #pragma unroll
        for (int rt = 0; rt < 3; ++rt)
            #pragma unroll
            for (int nt = 0; nt < 2; ++nt)
                pkV[rt][nt] = pack4(av[rt][nt]);

        // ---- QK^T fused with softmax per it-row block ----
        // S^T[j][i] = mfma(A=k, B=q); pi cancels (both operands share it).
        // Output C-layout is HW-fixed: lane holds S[i=it*16+lr][j=jt*16+4lc+reg]
        const float scale = 0.17677669529663689f;   // 1/sqrt(32)
        u64 pkP[3][3];
        float inv[3];
        #pragma unroll
        for (int it = 0; it < 3; ++it) {
            f32x4 sr[3];
            #pragma unroll
            for (int jt = 0; jt < 3; ++jt) {
                f32x4 z = {0.f, 0.f, 0.f, 0.f};
                sr[jt] = MFMA(kfr[jt], qfr[it], z);
            }
            float sum = 0.f;
            #pragma unroll
            for (int jt = 0; jt < 3; ++jt) {
                f32x4 pv;
                #pragma unroll
                for (int reg = 0; reg < 4; ++reg) {
                    float p = (jt == 2 && lc >= 2) ? 0.f : __expf(sr[jt][reg] * scale);  // mask j>=40
                    pv[reg] = p;
                    sum += p;
                }
                pkP[it][jt] = pack4(pv);
            }
            sum += __shfl_xor(sum, 16);
            sum += __shfl_xor(sum, 32);
            inv[it] = 1.f / sum;           // folded into epilogue (P unnormalized)
        }

        // prefetch next sample (covered by PV..B2..read-pass)
        if (s + 1 < SPB) {
            #pragma unroll
            for (int j = 0; j < 5; ++j)
                xp[j] = in4[(s0 + s + 1) * 1280 + t + 256 * j];
        }

        // ---- PV, transposed: O^T[e][i] = mfma(A=v^T, B=P) ----
        // kk=0: slots j = {4lc+s, 16+4lc+s-4}; kk=1: {32+4lc+s, 0-pad} —
        // A and B zero together on the pad slots, so pairing stays exact.
        f32x4 o[2][3];
        #pragma unroll
        for (int et = 0; et < 2; ++et)
            #pragma unroll
            for (int it = 0; it < 3; ++it)
                o[et][it] = f32x4{0.f, 0.f, 0.f, 0.f};
        #pragma unroll
        for (int kk = 0; kk < 2; ++kk) {
            s16x8 vfr[2], pfr[3];
            #pragma unroll
            for (int et = 0; et < 2; ++et)
                vfr[et] = kk ? cat(pkV[2][et], 0ull)
                             : cat(pkV[0][et], pkV[1][et]);
            #pragma unroll
            for (int it = 0; it < 3; ++it)
                pfr[it] = kk ? cat(pkP[it][2], 0ull)
                             : cat(pkP[it][0], pkP[it][1]);
            #pragma unroll
            for (int et = 0; et < 2; ++et)
                #pragma unroll
                for (int it = 0; it < 3; ++it)
                    o[et][it] = MFMA(vfr[et], pfr[it], o[et][it]);
        }

        // ---- epilogue: y = relu(o*inv + ar); LN partials; y -> ost ----
        #pragma unroll
        for (int it = 0; it < 3; ++it) {
            const bool valid = !(it == 2 && lr >= 8);      // rows < 40
            float sa = 0.f, qa2 = 0.f;
            float4 yv[2];
            #pragma unroll
            for (int et = 0; et < 2; ++et)
                #pragma unroll
                for (int reg = 0; reg < 4; ++reg) {
                    float yy = fmaxf(fmaf(o[et][it][reg], inv[it], ar[et][it][reg]), 0.f);
                    (&yv[et].x)[reg] = yy;
                    sa += yy;
                    qa2 = fmaf(yy, yy, qa2);
                }
            sa  += __shfl_xor(sa, 16);   sa  += __shfl_xor(sa, 32);
            qa2 += __shfl_xor(qa2, 16);  qa2 += __shfl_xor(qa2, 32);
            if (lc == 0)
                *reinterpret_cast<float2*>(&red[((it * 16 + lr) * 4 + w) * 2]) =
                    make_float2(sa, qa2);
            if (valid) {
                #pragma unroll
                for (int et = 0; et < 2; ++et)
                    *reinterpret_cast<float4*>(&ost[(it * 16 + lr) * OSTR + h * 32 + et * 16 + 4 * lc]) = yv[et];
            }
        }
        __syncthreads();                                   // B2: red + ost ready

        // ---- read-pass: stats from red (broadcast), LN affine, coalesced store ----
        const int c4r = t & 31;
        const float4 gvr = *reinterpret_cast<const float4*>(&ln_g[d * 128 + c4r * 4]);
        const float4 bvr = *reinterpret_cast<const float4*>(&ln_b[d * 128 + c4r * 4]);
        const size_t b4 = (s0 + s) * 1280;
        #pragma unroll
        for (int j5 = 0; j5 < 5; ++j5) {
            const int idx = j5 * 256 + t;
            const int row = idx >> 5;                      // (idx & 31) == c4r
            const float4 r01 = *reinterpret_cast<const float4*>(&red[row * 8]);
            const float4 r23 = *reinterpret_cast<const float4*>(&red[row * 8 + 4]);
            const float sa = r01.x + r01.z + r23.x + r23.z;
            const float q2 = r01.y + r01.w + r23.y + r23.w;
            const float mean = sa * (1.f / 128.f);
            const float rstd = rsqrtf(q2 * (1.f / 128.f) - mean * mean + 1e-6f);
            const float4 v = *reinterpret_cast<const float4*>(&ost[row * OSTR + c4r * 4]);
            float4 ov;
            ov.x = (v.x - mean) * rstd * gvr.x + bvr.x;
            ov.y = (v.y - mean) * rstd * gvr.y + bvr.y;
            ov.z = (v.z - mean) * rstd * gvr.z + bvr.z;
            ov.w = (v.w - mean) * rstd * gvr.w + bvr.w;
            out4g[b4 + idx] = ov;
        }
    }
}

extern "C" void kernel_launch(void* const* d_in, const int* in_sizes, int n_in,
                              void* d_out, int out_size, void* d_ws, size_t ws_size,
                              hipStream_t stream)
{
    const float* inputs = (const float*)d_in[0];
    const int*   dm     = (const int*)d_in[1];
    const float* Wq     = (const float*)d_in[2];
    const float* Wv     = (const float*)d_in[3];
    const float* Wr     = (const float*)d_in[4];
    const float* g      = (const float*)d_in[5];
    const float* bt     = (const float*)d_in[6];
    float* outp         = (float*)d_out;
    ushort* Wt          = (ushort*)d_ws;   // 6*128*128*2 = 192 KB

    convert_w<<<(6 * 16384 + 255) / 256, 256, 0, stream>>>(Wq, Wv, Wr, Wt);
    mdr_fused13<<<NBLK, NT, 0, stream>>>(inputs, dm, Wt, g, bt, outp);
}